// Round 5
// baseline (123.605 us; speedup 1.0000x reference)
//
#include <hip/hip_runtime.h>

// AttentionConv on MI355X (gfx950).
// prep A: split x into bf16 hi/lo planes (pixel layout).
// prep B: split W into bf16 hi/lo, fragment-major layout (lane-coalesced).
// phase1: per-patch QKV GEMM (M=32768,K=192,N=576) via bf16x3-split MFMA.
//         NO LDS, NO barriers: A,B fragments loaded direct global->reg.
//         Each lane holds matching q,k,v for same (j,dl); writes q and w=k*v.
// phase2: out = q * sum fr(di,pi)*fc(dj,pj) * w_shifted, LDS-tiled 64x64+8halo.

#define HW 512
#define PLANE 6291456   // 8*3*512*512 elements per plane

typedef __attribute__((ext_vector_type(8))) short bf16x8;
typedef __attribute__((ext_vector_type(4))) float f32x4;

static __device__ __forceinline__ unsigned short bf16_rne(float f) {
    unsigned u = __builtin_bit_cast(unsigned, f);
    u += 0x7FFFu + ((u >> 16) & 1u);
    return (unsigned short)(u >> 16);
}
static __device__ __forceinline__ float bf16f(unsigned short h) {
    unsigned u = ((unsigned)h) << 16;
    return __builtin_bit_cast(float, u);
}

// ---------- prep A: x -> xh, xl bf16 planes ----------
__global__ void __launch_bounds__(256) xsplit_kernel(
    const float* __restrict__ x,
    unsigned short* __restrict__ xh,
    unsigned short* __restrict__ xl)
{
    int gid = blockIdx.x * 256 + threadIdx.x;      // PLANE/8 threads
    const float4* s = (const float4*)x + (size_t)gid * 2;
    float4 a = s[0], b = s[1];
    float v[8] = {a.x, a.y, a.z, a.w, b.x, b.y, b.z, b.w};
    unsigned short h[8], lo[8];
    #pragma unroll
    for (int u = 0; u < 8; ++u) {
        h[u]  = bf16_rne(v[u]);
        lo[u] = bf16_rne(v[u] - bf16f(h[u]));
    }
    uint4 hp, lp;
    hp.x = (unsigned)h[0] | ((unsigned)h[1] << 16);
    hp.y = (unsigned)h[2] | ((unsigned)h[3] << 16);
    hp.z = (unsigned)h[4] | ((unsigned)h[5] << 16);
    hp.w = (unsigned)h[6] | ((unsigned)h[7] << 16);
    lp.x = (unsigned)lo[0] | ((unsigned)lo[1] << 16);
    lp.y = (unsigned)lo[2] | ((unsigned)lo[3] << 16);
    lp.z = (unsigned)lo[4] | ((unsigned)lo[5] << 16);
    lp.w = (unsigned)lo[6] | ((unsigned)lo[7] << 16);
    ((uint4*)xh)[gid] = hp;
    ((uint4*)xl)[gid] = lp;
}

// ---------- prep B: W -> fragment-major bf16 hi/lo ----------
// Ws layout (8-ushort entries): entry((ckt*2+half)*8 + kg, er) at
//   ((( (ckt*2+half)*8 + kg )*192 + er) * 8) ushorts; kg = ks*4+lk; er = slot*64+dl.
__global__ void __launch_bounds__(256) wprep_kernel(const float* __restrict__ W,
                                                    unsigned short* __restrict__ Ws)
{
    int gid = blockIdx.x * 256 + threadIdx.x;      // 13824 = 54*256 exact
    int er  = gid % 192;
    int t   = gid / 192;
    int kg  = t & 7;
    int ckt = t >> 3;                              // c*3 + kt, 0..8
    int c = ckt / 3, kt = ckt % 3;
    int slot = er >> 6, dl = er & 63;
    const float* src = W + (size_t)(slot*192 + c*64 + dl)*192 + kt*64 + kg*8;
    float4 a = ((const float4*)src)[0], b = ((const float4*)src)[1];
    float v[8] = {a.x, a.y, a.z, a.w, b.x, b.y, b.z, b.w};
    unsigned short h[8], lo[8];
    #pragma unroll
    for (int u = 0; u < 8; ++u) {
        h[u]  = bf16_rne(v[u]);
        lo[u] = bf16_rne(v[u] - bf16f(h[u]));
    }
    uint4 hp, lp;
    hp.x = (unsigned)h[0] | ((unsigned)h[1] << 16);
    hp.y = (unsigned)h[2] | ((unsigned)h[3] << 16);
    hp.z = (unsigned)h[4] | ((unsigned)h[5] << 16);
    hp.w = (unsigned)h[6] | ((unsigned)h[7] << 16);
    lp.x = (unsigned)lo[0] | ((unsigned)lo[1] << 16);
    lp.y = (unsigned)lo[2] | ((unsigned)lo[3] << 16);
    lp.z = (unsigned)lo[4] | ((unsigned)lo[5] << 16);
    lp.w = (unsigned)lo[6] | ((unsigned)lo[7] << 16);
    size_t oh = ((size_t)((ckt*2 + 0)*8 + kg)*192 + er) * 8;
    size_t ol = ((size_t)((ckt*2 + 1)*8 + kg)*192 + er) * 8;
    *(uint4*)(Ws + oh) = hp;
    *(uint4*)(Ws + ol) = lp;
}

// ---------- phase 1: LDS-free, barrier-free MFMA GEMM ----------
// grid (512, 3): blockIdx.x = b*64+i (tile-row), blockIdx.y = c (output channel).
// 4 waves; wave wv owns dl in [wv*16, wv*16+16); n=0,1,2 selects slot q,k,v.
__global__ void __launch_bounds__(256) qkv_mfma_kernel(
    const unsigned short* __restrict__ xh,
    const unsigned short* __restrict__ xl,
    const unsigned short* __restrict__ Ws,
    const float* __restrict__ bqkv,
    float* __restrict__ ws)
{
    const int tid = threadIdx.x;
    const int mb  = blockIdx.x;
    const int c   = blockIdx.y;
    const int b   = mb >> 6, i = mb & 63;
    const int wv  = tid >> 6;
    const int l   = tid & 63;
    const int lr  = l & 15;
    const int lk  = l >> 4;

    f32x4 acc[4][3];
    #pragma unroll
    for (int m = 0; m < 4; ++m)
        #pragma unroll
        for (int n = 0; n < 3; ++n)
            #pragma unroll
            for (int r = 0; r < 4; ++r) acc[m][n][r] = 0.f;

    #pragma unroll
    for (int kt = 0; kt < 3; ++kt) {
        const unsigned short* xhp = xh + ((size_t)(b*3 + kt)*HW + (size_t)i*8) * HW;
        const unsigned short* xlp = xl + ((size_t)(b*3 + kt)*HW + (size_t)i*8) * HW;
        const unsigned short* Bb  = Ws + (size_t)(c*3 + kt) * 2 * 8 * 192 * 8;
        #pragma unroll
        for (int ks = 0; ks < 2; ++ks) {
            const int pi = ks*4 + lk;                 // k-octet = pixel row pi
            bf16x8 ah[4], al[4];
            #pragma unroll
            for (int m = 0; m < 4; ++m) {
                int j = m*16 + lr;
                size_t o = (size_t)pi*HW + j*8;
                ah[m] = *(const bf16x8*)(xhp + o);
                al[m] = *(const bf16x8*)(xlp + o);
            }
            bf16x8 bh[3], bl[3];
            #pragma unroll
            for (int n = 0; n < 3; ++n) {
                int er = n*64 + wv*16 + lr;
                size_t oh = ((size_t)(0*8 + ks*4 + lk)*192 + er) * 8;
                size_t ol = ((size_t)(1*8 + ks*4 + lk)*192 + er) * 8;
                bh[n] = *(const bf16x8*)(Bb + oh);
                bl[n] = *(const bf16x8*)(Bb + ol);
            }
            #pragma unroll
            for (int m = 0; m < 4; ++m)
                #pragma unroll
                for (int n = 0; n < 3; ++n) {
                    acc[m][n] = __builtin_amdgcn_mfma_f32_16x16x32_bf16(al[m], bh[n], acc[m][n], 0, 0, 0);
                    acc[m][n] = __builtin_amdgcn_mfma_f32_16x16x32_bf16(ah[m], bl[n], acc[m][n], 0, 0, 0);
                    acc[m][n] = __builtin_amdgcn_mfma_f32_16x16x32_bf16(ah[m], bh[n], acc[m][n], 0, 0, 0);
                }
        }
    }

    // ---- epilogue: in-register w = k*v; direct dword stores ----
    const int dl = wv*16 + lr;
    const float bq = bqkv[      c*64 + dl];
    const float bk = bqkv[192 + c*64 + dl];
    const float bv = bqkv[384 + c*64 + dl];
    const int ppi = dl >> 3, ppj = dl & 7;
    float* qplane = ws;
    float* wplane = ws + PLANE;
    size_t rowoff = ((size_t)(b*3 + c)*HW + (size_t)(i*8 + ppi))*HW + ppj;
    #pragma unroll
    for (int m = 0; m < 4; ++m)
        #pragma unroll
        for (int ri = 0; ri < 4; ++ri) {
            int j = m*16 + lk*4 + ri;               // D row = (l>>4)*4 + reg
            float qv = acc[m][0][ri] + bq;
            float wvv = (acc[m][1][ri] + bk) * (acc[m][2][ri] + bv);
            qplane[rowoff + (size_t)j*8] = qv;
            wplane[rowoff + (size_t)j*8] = wvv;
        }
}

// ---------- phase 2: LDS-tiled 9-tap stencil, hoisted exps ----------
__global__ void __launch_bounds__(256) attn_kernel(
    const float* __restrict__ ws,
    const float* __restrict__ bqkv,
    float* __restrict__ out)
{
    __shared__ float wt[80][84];
    const int tid = threadIdx.x;
    int bid = blockIdx.x;
    int txt = (bid & 7) << 6;
    int tyt = ((bid >> 3) & 7) << 6;
    int pl  = bid >> 6;                           // b*3 + c
    int c   = pl % 3;
    const float* qplane = ws + (size_t)pl * (HW*HW);
    const float* wplane = ws + PLANE + (size_t)pl * (HW*HW);

    // iteration-invariant bias factors (pi, pj0 don't depend on it)
    const int pi  = (tid >> 4) & 7;
    const int pj0 = (tid & 1) << 2;
    const float fr0 = __expf((float)(pi - 7) * 0.25f);
    const float fr2 = __expf((float)(-pi) * 0.25f);
    float fa[4], fb[4];
    #pragma unroll
    for (int u = 0; u < 4; ++u) {
        int pj = pj0 + u;
        fa[u] = __expf((float)(pj - 7) * 0.25f);
        fb[u] = __expf((float)(-pj) * 0.25f);
    }

    for (int it = 0; it < 7; ++it) {
        int f = tid + it*256;
        if (f < 1600) {                           // 80 rows x 20 float4
            int r  = f / 20;
            int c4 = f - r*20;
            int gy = tyt - 8 + r;
            int gx = txt - 8 + (c4 << 2);
            float4 v;
            if ((unsigned)gy < 512u && (unsigned)gx < 512u) {
                v = *(const float4*)(wplane + (size_t)gy*HW + gx);
            } else {
                int d0 = c*64 + (gy & 7)*8 + (gx & 7);
                float4 bk = *(const float4*)(bqkv + 192 + d0);
                float4 bv = *(const float4*)(bqkv + 384 + d0);
                v.x = bk.x*bv.x; v.y = bk.y*bv.y; v.z = bk.z*bv.z; v.w = bk.w*bv.w;
            }
            *(float4*)&wt[r][c4 << 2] = v;
        }
    }
    __syncthreads();

    #pragma unroll
    for (int it = 0; it < 4; ++it) {
        int f  = tid + it*256;
        int ly = f >> 4;
        int lx = (f & 15) << 2;
        float sx = 0.f, sy = 0.f, sz = 0.f, sw = 0.f;
        #pragma unroll
        for (int di = 0; di < 3; ++di) {
            const float* row = &wt[ly + 8*di][lx];
            float4 w0 = *(const float4*)(row);
            float4 w1 = *(const float4*)(row + 8);
            float4 w2 = *(const float4*)(row + 16);
            float fr = (di == 0) ? fr0 : (di == 1) ? 1.f : fr2;
            sx += fr * (fa[0]*w0.x + w1.x + fb[0]*w2.x);
            sy += fr * (fa[1]*w0.y + w1.y + fb[1]*w2.y);
            sz += fr * (fa[2]*w0.z + w1.z + fb[2]*w2.z);
            sw += fr * (fa[3]*w0.w + w1.w + fb[3]*w2.w);
        }
        size_t off = (size_t)pl*(HW*HW) + (size_t)(tyt + ly)*HW + txt + lx;
        float4 q4 = *(const float4*)(qplane + (size_t)(tyt + ly)*HW + txt + lx);
        float4 o;
        o.x = q4.x*sx; o.y = q4.y*sy; o.z = q4.z*sz; o.w = q4.w*sw;
        *(float4*)(out + off) = o;
    }
}

extern "C" void kernel_launch(void* const* d_in, const int* in_sizes, int n_in,
                              void* d_out, int out_size, void* d_ws, size_t ws_size,
                              hipStream_t stream)
{
    const float* x  = (const float*)d_in[0];   // [8][3][512][512]
    const float* W  = (const float*)d_in[1];   // [576][192]
    const float* bq = (const float*)d_in[2];   // [576]
    float* wsf = (float*)d_ws;
    // layout: q-plane f32 | w-plane f32 | xh bf16 | xl bf16 | Wsplit  (~76 MB)
    unsigned short* xh = (unsigned short*)(wsf + 2*(size_t)PLANE);
    unsigned short* xl = xh + PLANE;
    unsigned short* Wsplit = xl + PLANE;

    xsplit_kernel<<<3072, 256, 0, stream>>>(x, xh, xl);
    wprep_kernel<<<54, 256, 0, stream>>>(W, Wsplit);
    qkv_mfma_kernel<<<dim3(512, 3), 256, 0, stream>>>(xh, xl, Wsplit, bq, wsf);
    attn_kernel<<<1536, 256, 0, stream>>>(wsf, bq, (float*)d_out);
}